// Round 10
// baseline (277.193 us; speedup 1.0000x reference)
//
#include <hip/hip_runtime.h>
#include <hip/hip_bf16.h>

typedef __hip_bfloat16 bf16;
typedef unsigned short u16;
typedef __attribute__((ext_vector_type(8))) short short8;
typedef __attribute__((ext_vector_type(4))) short short4v;
typedef __attribute__((ext_vector_type(4))) float f32x4;

#define D_MODEL 1024
#define NUM_HEADS 16
#define DEPTH 64
#define BATCH 4
#define SEQ 1024
#define BS (BATCH * SEQ)

__device__ __forceinline__ float ldDyn(const void* p, size_t i, int isbf) {
  return isbf ? __bfloat162float(((const bf16*)p)[i]) : ((const float*)p)[i];
}
__device__ __forceinline__ u16 f2bf(float f) {
  bf16 h = __float2bfloat16(f);
  return *(u16*)&h;
}
// async global->LDS, 16B per lane; LDS dest = wave-uniform base + lane*16
__device__ __forceinline__ void gl2lds16(const void* g, void* l) {
  __builtin_amdgcn_global_load_lds((const __attribute__((address_space(1))) unsigned int*)g,
                                   (__attribute__((address_space(3))) unsigned int*)l, 16, 0, 0);
}

// Per-wave dtype detection via ballot: lane i checks q[2i]; one load/thread.
__device__ __forceinline__ int detect_isbf(const u16* q) {
  const int lane = threadIdx.x & 63;
  u16 h = q[2 * lane];
  int e = (h >> 7) & 0xFF;
  unsigned long long m = __ballot(e >= 100 && e <= 150);
  return (__popcll(m) >= 48) ? 1 : 0;
}

// Merged prep kernel (detect + convert + weight transpose in one launch).
// z < 4: convert q/k/v/pos to bf16. z in [4,10): transpose weight z-4.
__global__ __launch_bounds__(256) void prep(
    const void* __restrict__ q, const void* __restrict__ k, const void* __restrict__ v,
    const void* __restrict__ pos, const void* __restrict__ W0, const void* __restrict__ W1,
    const void* __restrict__ W2, const void* __restrict__ W3, const void* __restrict__ W4,
    const void* __restrict__ W5, u16* __restrict__ Qb, u16* __restrict__ Kb,
    u16* __restrict__ Vb, u16* __restrict__ Pb, u16* __restrict__ WT,
    int* __restrict__ flag) {
  const int isbf = detect_isbf((const u16*)q);
  const int z = blockIdx.z;
  const int t = threadIdx.x;
  if (z == 0 && blockIdx.x == 0 && t == 0) *flag = isbf;

  if (z < 4) {
    const void* src = (z == 0) ? q : (z == 1) ? k : (z == 2) ? v : pos;
    u16* dst = (z == 0) ? Qb : (z == 1) ? Kb : (z == 2) ? Vb : Pb;
    const size_t n8 = ((z == 3) ? (size_t)SEQ * D_MODEL : (size_t)BS * D_MODEL) / 8;
    for (size_t i = (size_t)blockIdx.x * 256 + t; i < n8; i += (size_t)gridDim.x * 256) {
      short8 o;
      if (isbf) {
        o = ((const short8*)src)[i];
      } else {
        const float4* f = (const float4*)src + 2 * i;
        float4 lo = f[0], hi = f[1];
        u16* pv = (u16*)&o;
        pv[0] = f2bf(lo.x); pv[1] = f2bf(lo.y); pv[2] = f2bf(lo.z); pv[3] = f2bf(lo.w);
        pv[4] = f2bf(hi.x); pv[5] = f2bf(hi.y); pv[6] = f2bf(hi.z); pv[7] = f2bf(hi.w);
      }
      ((short8*)dst)[i] = o;
    }
  } else {
    const int w = z - 4;
    const void* W = (w == 0) ? W0 : (w == 1) ? W1 : (w == 2) ? W2
                   : (w == 3) ? W3 : (w == 4) ? W4 : W5;
    u16* out = WT + (size_t)w * D_MODEL * D_MODEL;
    __shared__ u16 tile[32][33];
    const int tx = t & 31, ty = t >> 5;
    const int r0 = (blockIdx.x >> 5) * 32, c0 = (blockIdx.x & 31) * 32;
#pragma unroll
    for (int i = 0; i < 4; ++i) {
      size_t gi = (size_t)(r0 + ty + 8 * i) * D_MODEL + c0 + tx;
      tile[ty + 8 * i][tx] = isbf ? ((const u16*)W)[gi] : f2bf(((const float*)W)[gi]);
    }
    __syncthreads();
    // vectorized writeback: one short4 (8B) store per thread
    const int orow = t >> 3, cg = t & 7;
    short4v pk;
#pragma unroll
    for (int j = 0; j < 4; ++j) pk[j] = (short)tile[cg * 4 + j][orow];
    *(short4v*)&out[(size_t)(c0 + orow) * 1024 + r0 + cg * 4] = pk;
  }
}

struct GArgs {
  const u16* A[5];
  const u16* W[5];
  const void* bias[5];
  void* C[5];
  int Mr[5];
  int om[5];
};

// ---------------- g1 kernel: 256x256 tile, 8 waves, split-step ----------------
// At the m233 2-phase structural ceiling (~607 TF). Counted vmcnt(4) boundary;
// never drained to 0 inside the loop.
__global__ __launch_bounds__(512, 2) void gemm_big(GArgs ga, const int* __restrict__ flagp) {
  const int isbf = *flagp;
  const int z = blockIdx.z;
  const int M = ga.Mr[z];
  const int lin = blockIdx.x + 4 * blockIdx.y;  // 0..63
  const int xcd = lin & 7;
  const int idx = lin >> 3;                     // 0..7
  int rowb, colb;
  if (M >= 4096) {
    rowb = xcd * 2 + (idx & 1);                 // 0..15
    colb = idx >> 1;                            // 0..3
  } else {
    if (idx >= 2) return;
    rowb = idx * 2 + (xcd & 1);                 // 0..3
    colb = xcd >> 1;                            // 0..3
  }
  const int row0 = rowb * 256, col0 = colb * 256;
  if (row0 >= M) return;
  const u16* A = ga.A[z];
  const u16* WT = ga.W[z];
  const void* bias = ga.bias[z];
  void* C = ga.C[z];
  const int omode = ga.om[z];

  __shared__ short As[3][256][32];  // 48 KB
  __shared__ short Bs[3][256][32];  // 48 KB
  const int t = threadIdx.x;                    // 0..511
  const int wave = t >> 6, lane = t & 63;
  const int quad = lane >> 4, c16 = lane & 15;
  const int wrow = wave >> 2;                   // 0..1 : 128-row strip
  const int wcol = wave & 3;                    // 0..3 : 64-col strip

  f32x4 acc[8][4];
#pragma unroll
  for (int mt = 0; mt < 8; ++mt)
#pragma unroll
    for (int nt = 0; nt < 4; ++nt) acc[mt][nt] = {0.f, 0.f, 0.f, 0.f};

#define STAGE_A(K0, BUF)                                                                  \
  {                                                                                       \
    _Pragma("unroll") for (int j = 0; j < 2; ++j) {                                       \
      int L = t + 512 * j;                                                                \
      int r = L >> 2;                                                                     \
      int kc = (L & 3) ^ ((r + (r >> 2)) & 3);                                            \
      gl2lds16(A + (size_t)(row0 + r) * 1024 + (K0) + kc * 8,                             \
               (char*)&As[BUF][0][0] + (size_t)(j * 512 + wave * 64) * 16);               \
    }                                                                                     \
  }
#define STAGE_B(K0, BUF)                                                                  \
  {                                                                                       \
    _Pragma("unroll") for (int j = 0; j < 2; ++j) {                                       \
      int L = t + 512 * j;                                                                \
      int r = L >> 2;                                                                     \
      int kc = (L & 3) ^ ((r + (r >> 2)) & 3);                                            \
      gl2lds16(WT + (size_t)(col0 + r) * 1024 + (K0) + kc * 8,                            \
               (char*)&Bs[BUF][0][0] + (size_t)(j * 512 + wave * 64) * 16);               \
    }                                                                                     \
  }

  const int fsw = (c16 + (c16 >> 2)) & 3;  // = f(row) for row = base16k + c16

  STAGE_A(0, 0);
  STAGE_B(0, 0);
  STAGE_A(32, 1);
  STAGE_B(32, 1);
#pragma unroll
  for (int kk = 0; kk < 31; ++kk) {
    const int cur = kk % 3;
    const int pre = (kk + 2) % 3;
    asm volatile("s_waitcnt vmcnt(4)\n\ts_barrier" ::: "memory");

    short8 bfv[4], afl[4], afh[4];
    // ---- sub-phase 1: stage A(k+2) || read bfv + af-low -> 16 MFMA ----
    if (kk < 30) STAGE_A((kk + 2) * 32, pre);
#pragma unroll
    for (int nt = 0; nt < 4; ++nt)
      bfv[nt] = *(const short8*)&Bs[cur][wcol * 64 + nt * 16 + c16][((quad ^ fsw) * 8)];
#pragma unroll
    for (int mt = 0; mt < 4; ++mt)
      afl[mt] = *(const short8*)&As[cur][wrow * 128 + mt * 16 + c16][((quad ^ fsw) * 8)];
    __builtin_amdgcn_s_setprio(1);
#pragma unroll
    for (int nt = 0; nt < 4; ++nt)
#pragma unroll
      for (int mt = 0; mt < 4; ++mt)
        acc[mt][nt] = __builtin_amdgcn_mfma_f32_16x16x32_bf16(afl[mt], bfv[nt], acc[mt][nt], 0, 0, 0);
    __builtin_amdgcn_s_setprio(0);

    asm volatile("s_barrier" ::: "memory");  // role-split boundary

    // ---- sub-phase 2: stage B(k+2) || read af-high -> 16 MFMA ----
    if (kk < 30) STAGE_B((kk + 2) * 32, pre);
#pragma unroll
    for (int mt = 0; mt < 4; ++mt)
      afh[mt] = *(const short8*)&As[cur][wrow * 128 + 64 + mt * 16 + c16][((quad ^ fsw) * 8)];
    __builtin_amdgcn_s_setprio(1);
#pragma unroll
    for (int nt = 0; nt < 4; ++nt)
#pragma unroll
      for (int mt = 0; mt < 4; ++mt)
        acc[mt + 4][nt] = __builtin_amdgcn_mfma_f32_16x16x32_bf16(afh[mt], bfv[nt], acc[mt + 4][nt], 0, 0, 0);
    __builtin_amdgcn_s_setprio(0);
  }
  asm volatile("s_waitcnt vmcnt(0)\n\ts_barrier" ::: "memory");
  {
    short8 bfv[4], af[8];
#pragma unroll
    for (int nt = 0; nt < 4; ++nt)
      bfv[nt] = *(const short8*)&Bs[1][wcol * 64 + nt * 16 + c16][((quad ^ fsw) * 8)];
#pragma unroll
    for (int mt = 0; mt < 8; ++mt)
      af[mt] = *(const short8*)&As[1][wrow * 128 + mt * 16 + c16][((quad ^ fsw) * 8)];
#pragma unroll
    for (int nt = 0; nt < 4; ++nt)
#pragma unroll
      for (int mt = 0; mt < 8; ++mt)
        acc[mt][nt] = __builtin_amdgcn_mfma_f32_16x16x32_bf16(af[mt], bfv[nt], acc[mt][nt], 0, 0, 0);
  }
#undef STAGE_A
#undef STAGE_B

#pragma unroll
  for (int nt = 0; nt < 4; ++nt) {
    int gc = col0 + wcol * 64 + nt * 16 + c16;
    float bb = ldDyn(bias, gc, isbf);
#pragma unroll
    for (int mt = 0; mt < 8; ++mt) {
      int gr0 = row0 + wrow * 128 + mt * 16 + quad * 4;
      if (omode == 2) {
        short4v pk;
#pragma unroll
        for (int r = 0; r < 4; ++r) pk[r] = (short)f2bf(acc[mt][nt][r] + bb);
        *(short4v*)&((u16*)C)[(size_t)gc * M + gr0] = pk;
      } else if (omode == 1 || isbf) {
#pragma unroll
        for (int r = 0; r < 4; ++r)
          ((bf16*)C)[(size_t)(gr0 + r) * 1024 + gc] = __float2bfloat16(acc[mt][nt][r] + bb);
      } else {
#pragma unroll
        for (int r = 0; r < 4; ++r)
          ((float*)C)[(size_t)(gr0 + r) * 1024 + gc] = acc[mt][nt][r] + bb;
      }
    }
  }
}

// ---------------- g2 kernel: 128x128 tile, 8 waves (round-4 structure) --------
__global__ __launch_bounds__(512) void gemm_128(GArgs ga, const int* __restrict__ flagp) {
  const int isbf = *flagp;
  const int z = blockIdx.z;
  const int M = ga.Mr[z];
  const int lin = blockIdx.x + 8 * blockIdx.y;  // 0..255
  const int xcd = lin & 7;
  const int loc = lin >> 3;                     // 0..31
  const int rowb = (loc & 3) * 8 + xcd;         // 0..31
  const int colb = loc >> 2;                    // 0..7
  const int row0 = rowb * 128, col0 = colb * 128;
  if (row0 >= M) return;
  const u16* A = ga.A[z];
  const u16* WT = ga.W[z];
  const void* bias = ga.bias[z];
  void* C = ga.C[z];
  const int omode = ga.om[z];

  __shared__ short As[3][128][32];  // 24 KB
  __shared__ short Bs[3][128][32];  // 24 KB
  const int t = threadIdx.x;                    // 0..511
  const int wave = t >> 6, lane = t & 63;
  const int quad = lane >> 4, c16 = lane & 15;
  const int wrow = wave >> 2;                   // 0..1 : 64-row strip
  const int wcol = wave & 3;                    // 0..3 : 32-col strip

  f32x4 acc[4][2];
#pragma unroll
  for (int mt = 0; mt < 4; ++mt)
#pragma unroll
    for (int nt = 0; nt < 2; ++nt) acc[mt][nt] = {0.f, 0.f, 0.f, 0.f};

#define G_STAGE(K0, BUF)                                                                  \
  {                                                                                       \
    int r = t >> 2;                                                                       \
    int kc = (t & 3) ^ ((r + (r >> 2)) & 3);                                              \
    gl2lds16(A + (size_t)(row0 + r) * 1024 + (K0) + kc * 8,                               \
             (char*)&As[BUF][0][0] + (size_t)(wave * 64) * 16);                           \
    gl2lds16(WT + (size_t)(col0 + r) * 1024 + (K0) + kc * 8,                              \
             (char*)&Bs[BUF][0][0] + (size_t)(wave * 64) * 16);                           \
  }

  const int fsw = (c16 + (c16 >> 2)) & 3;

#define COMPUTE(BUF)                                                                      \
  {                                                                                       \
    short8 af[4], bfv[2];                                                                 \
    _Pragma("unroll") for (int mt = 0; mt < 4; ++mt)                                      \
        af[mt] = *(const short8*)&As[BUF][wrow * 64 + mt * 16 + c16][((quad ^ fsw) * 8)]; \
    _Pragma("unroll") for (int nt = 0; nt < 2; ++nt)                                      \
        bfv[nt] = *(const short8*)&Bs[BUF][wcol * 32 + nt * 16 + c16][((quad ^ fsw) * 8)];\
    _Pragma("unroll") for (int nt = 0; nt < 2; ++nt)                                      \
      _Pragma("unroll") for (int mt = 0; mt < 4; ++mt)                                    \
          acc[mt][nt] =                                                                   \
              __builtin_amdgcn_mfma_f32_16x16x32_bf16(af[mt], bfv[nt], acc[mt][nt], 0, 0, 0); \
  }

  G_STAGE(0, 0);
  G_STAGE(32, 1);
#pragma unroll
  for (int kk = 0; kk < 31; ++kk) {
    asm volatile("s_waitcnt vmcnt(2)\n\ts_barrier" ::: "memory");
    if (kk < 30) G_STAGE((kk + 2) * 32, (kk + 2) % 3);
    COMPUTE(kk % 3);
  }
  asm volatile("s_waitcnt vmcnt(0)\n\ts_barrier" ::: "memory");
  COMPUTE(1);  // 31 % 3
#undef G_STAGE
#undef COMPUTE

#pragma unroll
  for (int nt = 0; nt < 2; ++nt) {
    int gc = col0 + wcol * 32 + nt * 16 + c16;
    float bb = ldDyn(bias, gc, isbf);
#pragma unroll
    for (int mt = 0; mt < 4; ++mt) {
      int gr0 = row0 + wrow * 64 + mt * 16 + quad * 4;
      if (omode == 2) {
        short4v pk;
#pragma unroll
        for (int r = 0; r < 4; ++r) pk[r] = (short)f2bf(acc[mt][nt][r] + bb);
        *(short4v*)&((u16*)C)[(size_t)gc * M + gr0] = pk;
      } else if (omode == 1 || isbf) {
#pragma unroll
        for (int r = 0; r < 4; ++r)
          ((bf16*)C)[(size_t)(gr0 + r) * 1024 + gc] = __float2bfloat16(acc[mt][nt][r] + bb);
      } else {
#pragma unroll
        for (int r = 0; r < 4; ++r)
          ((float*)C)[(size_t)(gr0 + r) * 1024 + gc] = acc[mt][nt][r] + bb;
      }
    }
  }
}

// Flash attention, round-10: the r9 kernel with the q-tile halved (128 -> 64
// rows), mt strip loop removed. r9 taught: flash was GRID-limited (512 blocks
// = exactly 2 blocks/CU; the 48 KB LDS already admits 3). Grid z doubles to 16
// -> 1024 blocks -> LDS-capped 3 blocks/CU = 3 waves/SIMD (was 2): 1.5x
// cross-wave overlap for the serial MFMA->softmax->PV chain (VALU 35 / Mfma 20,
// nothing saturated). Staging macros, swizzles, Pt geometry, barriers, theta
// logic ALL byte-identical to the r9-proven kernel; only the mt dimension is
// deleted and qrow rebased to qt*64 + wave*16. K/V HBM re-reads double
// (14.5 -> ~29 MB/dispatch) -- free at 5.9% HBM utilization.
__global__ __launch_bounds__(256) void flash_attn(
    const bf16* __restrict__ Qc, const bf16* __restrict__ Kc, const bf16* __restrict__ VcT,
    const bf16* __restrict__ Qp, const bf16* __restrict__ Kp,
    const void* __restrict__ th_cc, const void* __restrict__ th_co,
    const void* __restrict__ th_oc, bf16* __restrict__ O, const int* __restrict__ flagp) {
  const int isbf = *flagp;
  const int h = blockIdx.x, b = blockIdx.y, qt = blockIdx.z;
  const int t = threadIdx.x, wave = t >> 6, lane = t & 63;
  const int quad = lane >> 4, c16 = lane & 15;

  __shared__ short Kt[2][64][128];  // 32 KB, slot kc holds chunk kc^(key&15)
  __shared__ short Vt[64][64];      // 8 KB single-buffer, slot kc holds chunk kc^(d&7)
  __shared__ short Pt[4][16][64];   // 8 KB per-wave P strip, swizzled ^ (row&7)

  const float tcc = ldDyn(th_cc, h, isbf);
  const float tco = ldDyn(th_co, h, isbf);
  const float toc = ldDyn(th_oc, h, isbf);

  const bf16* kcb = Kc + (size_t)b * SEQ * 1024 + h * 64;
  const bf16* kpb = Kp + h * 64;
  const bf16* vtb = VcT + (size_t)(h * 64) * BS + (size_t)b * SEQ;

  // staging lane roles (unchanged from r9)
  const int rwK = lane >> 4, kcK = lane & 15;  // K-hat: 4 rows/inst, 16 chunks/row
  const int rwV = lane >> 3, kcV = lane & 7;   // V^T : 8 rows/inst,  8 chunks/row

#define STAGE_K(KT2, BUF)                                                              \
  {                                                                                    \
    _Pragma("unroll") for (int i = 0; i < 4; ++i) {                                    \
      int r = wave * 16 + i * 4 + rwK;                                                 \
      int c = kcK ^ (r & 15);                                                          \
      int key = (KT2)*64 + r;                                                          \
      const bf16* src = (c < 8) ? kcb + (size_t)key * 1024 + c * 8                     \
                                : kpb + (size_t)key * 1024 + c * 8 - 64;               \
      gl2lds16(src, &Kt[BUF][wave * 16 + i * 4][0]);                                   \
    }                                                                                  \
  }
#define STAGE_V(KT2)                                                                   \
  {                                                                                    \
    _Pragma("unroll") for (int j = 0; j < 2; ++j) {                                    \
      int d = wave * 16 + j * 8 + rwV;                                                 \
      int c = kcV ^ (d & 7);                                                           \
      gl2lds16(vtb + (size_t)d * BS + (KT2)*64 + c * 8, &Vt[wave * 16 + j * 8][0]);    \
    }                                                                                  \
  }

  // Q A-frags (register-resident, 1 strip of 16 q-rows per wave)
  short8 qf[4];
  {
    int qrow = qt * 64 + wave * 16 + c16;
#pragma unroll
    for (int ks = 0; ks < 4; ++ks) {
      int d = ks * 32 + quad * 8;
      const bf16* src = (d < 64) ? Qc + ((size_t)(b * SEQ + qrow)) * 1024 + h * 64 + d
                                 : Qp + (size_t)qrow * 1024 + h * 64 + (d - 64);
      qf[ks] = *(const short8*)src;
    }
    if (qrow == 0) {  // zero pos-half for q==0 (theta replaces pos there)
      qf[2] = (short8)0;
      qf[3] = (short8)0;
    }
  }

  f32x4 accO[4];
#pragma unroll
  for (int nt = 0; nt < 4; ++nt) accO[nt] = {0.f, 0.f, 0.f, 0.f};
  float lrow[4] = {0.f, 0.f, 0.f, 0.f};

  // prologue: stage tile 0, drain, zero key-0 pos-half (theta replaces it)
  STAGE_K(0, 0);
  STAGE_V(0);
  __syncthreads();
  if (t < 8) *(short8*)&Kt[0][0][64 + t * 8] = (short8)0;  // row0 swizzle = identity
  __syncthreads();

  for (int kt = 0; kt < 16; ++kt) {
    const int cur = kt & 1, nxt = cur ^ 1;
    if (kt < 15) STAGE_K(kt + 1, nxt);

    // ---- S = Q-hat (16x128) x K-hat^T from LDS ----
    f32x4 accS[4];
#pragma unroll
    for (int nt = 0; nt < 4; ++nt) accS[nt] = {0.f, 0.f, 0.f, 0.f};
    __builtin_amdgcn_s_setprio(1);
#pragma unroll
    for (int nt = 0; nt < 4; ++nt)
#pragma unroll
      for (int ks = 0; ks < 4; ++ks) {
        short8 kf = *(const short8*)&Kt[cur][nt * 16 + c16][((ks * 4 + quad) ^ c16) * 8];
        accS[nt] = __builtin_amdgcn_mfma_f32_16x16x32_bf16(qf[ks], kf, accS[nt], 0, 0, 0);
      }
    __builtin_amdgcn_s_setprio(0);

    // ---- V frags to registers ----
    short8 vbreg[2][4];
#pragma unroll
    for (int ks2 = 0; ks2 < 2; ++ks2)
#pragma unroll
      for (int nt = 0; nt < 4; ++nt)
        vbreg[ks2][nt] =
            *(const short8*)&Vt[nt * 16 + c16][(((ks2 * 4 + quad) ^ (c16 & 7)) & 7) * 8];

    // all waves have V(kt) in registers; then overwrite Vt with V(kt+1).
    // raw lgkmcnt-only wait: the in-flight K DMA (vmcnt) is NOT drained.
    asm volatile("s_waitcnt lgkmcnt(0)\n\ts_barrier" ::: "memory");
    if (kt < 15) STAGE_V(kt + 1);

    // ---- softmax-lite + P roundtrip + PV ----
    float s[4][4];
#pragma unroll
    for (int nt = 0; nt < 4; ++nt)
#pragma unroll
      for (int r = 0; r < 4; ++r) s[nt][r] = accS[nt][r] * 0.125f;

    if (kt == 0 || (qt == 0 && wave == 0)) {
#pragma unroll
      for (int nt = 0; nt < 4; ++nt)
#pragma unroll
        for (int r = 0; r < 4; ++r) {
          int kcol = kt * 64 + nt * 16 + c16;
          int qrow = qt * 64 + wave * 16 + quad * 4 + r;
          float add = 0.f;
          if (qrow == 0 && kcol == 0) add = tcc;
          else if (qrow == 0) add = tco;
          else if (kcol == 0) add = toc;
          s[nt][r] += add * 0.125f;
        }
    }
#pragma unroll
    for (int nt = 0; nt < 4; ++nt)
#pragma unroll
      for (int r = 0; r < 4; ++r) {
        float p = __expf(s[nt][r]);
        lrow[r] += p;
        int row = quad * 4 + r;
        int ch = nt * 2 + (c16 >> 3);
        Pt[wave][row][((ch ^ (row & 7)) * 8) + (c16 & 7)] = (short)f2bf(p);
      }
    __builtin_amdgcn_s_setprio(1);
#pragma unroll
    for (int ks2 = 0; ks2 < 2; ++ks2) {
      short8 pf = *(const short8*)&Pt[wave][c16][(((ks2 * 4 + quad) ^ (c16 & 7)) & 7) * 8];
#pragma unroll
      for (int nt = 0; nt < 4; ++nt)
        accO[nt] = __builtin_amdgcn_mfma_f32_16x16x32_bf16(pf, vbreg[ks2][nt], accO[nt], 0, 0, 0);
    }
    __builtin_amdgcn_s_setprio(0);

    __syncthreads();  // drains K and V DMA; protects buffer reuse
  }

  // one deferred l-reduction across the 16 c16 lanes
#pragma unroll
  for (int d = 1; d < 16; d <<= 1)
#pragma unroll
    for (int r = 0; r < 4; ++r) lrow[r] += __shfl_xor(lrow[r], d, 64);

#pragma unroll
  for (int nt = 0; nt < 4; ++nt)
#pragma unroll
    for (int r = 0; r < 4; ++r) {
      int qrow = qt * 64 + wave * 16 + quad * 4 + r;
      O[((size_t)(b * SEQ + qrow)) * 1024 + h * 64 + nt * 16 + c16] =
          __float2bfloat16(accO[nt][r] / lrow[r]);
    }
#undef STAGE_K
#undef STAGE_V
}

extern "C" void kernel_launch(void* const* d_in, const int* in_sizes, int n_in,
                              void* d_out, int out_size, void* d_ws, size_t ws_size,
                              hipStream_t stream) {
  const void* q = d_in[0];
  const void* k = d_in[1];
  const void* v = d_in[2];
  const void* Wq = d_in[3];
  const void* bq = d_in[4];
  const void* Wk = d_in[5];
  const void* bk = d_in[6];
  const void* Wv = d_in[7];
  const void* bv = d_in[8];
  const void* Uq = d_in[9];
  const void* buq = d_in[10];
  const void* Uk = d_in[11];
  const void* buk = d_in[12];
  const void* pos = d_in[13];
  const void* th_cc = d_in[14];
  const void* th_co = d_in[15];
  const void* th_oc = d_in[16];
  const void* Wo = d_in[17];
  const void* bo = d_in[18];

  const int M = BS;  // 4096
  const size_t DD = (size_t)D_MODEL * D_MODEL;
  char* wsb = (char*)d_ws;
  int* flag = (int*)wsb;
  bf16* Qc = (bf16*)(wsb + 256);            // 8 MB
  bf16* Kc = Qc + (size_t)M * D_MODEL;      // 8 MB
  bf16* VcT = Kc + (size_t)M * D_MODEL;     // 8 MB, [D_MODEL][M]
  bf16* Qp = VcT + (size_t)M * D_MODEL;     // 2 MB
  bf16* Kp = Qp + (size_t)SEQ * D_MODEL;    // 2 MB
  u16* WT = (u16*)(Kp + (size_t)SEQ * D_MODEL);  // 6 x 2 MB
  bf16* AO = (bf16*)WT;  // aliases WqT..UqT (dead after g1); WoT (slot 5) untouched
  u16* Qb = WT + 6 * DD;                    // 8 MB bf16 copies of activations
  u16* Kb = Qb + (size_t)M * D_MODEL;       // 8 MB
  u16* Vb = Kb + (size_t)M * D_MODEL;       // 8 MB
  u16* Pb = Vb + (size_t)M * D_MODEL;       // 2 MB (first SEQ rows of pos_table)

  prep<<<dim3(1024, 1, 10), dim3(256), 0, stream>>>(q, k, v, pos, Wq, Wk, Wv, Uq, Uk, Wo,
                                                    Qb, Kb, Vb, Pb, WT, flag);

  GArgs g1 = {{Qb, Kb, Vb, Pb, Pb},
              {WT + 0 * DD, WT + 1 * DD, WT + 2 * DD, WT + 3 * DD, WT + 4 * DD},
              {bq, bk, bv, buq, buk},
              {Qc, Kc, VcT, Qp, Kp},
              {M, M, M, SEQ, SEQ},
              {1, 1, 2, 1, 1}};
  gemm_big<<<dim3(4, 16, 5), dim3(512), 0, stream>>>(g1, flag);

  flash_attn<<<dim3(NUM_HEADS, BATCH, SEQ / 64), dim3(256), 0, stream>>>(
      Qc, Kc, VcT, Qp, Kp, th_cc, th_co, th_oc, AO, flag);

  GArgs g2 = {{(const u16*)AO, (const u16*)AO, (const u16*)AO, (const u16*)AO, (const u16*)AO},
              {WT + 5 * DD, WT + 5 * DD, WT + 5 * DD, WT + 5 * DD, WT + 5 * DD},
              {bo, bo, bo, bo, bo},
              {d_out, d_out, d_out, d_out, d_out},
              {M, M, M, M, M},
              {0, 0, 0, 0, 0}};
  gemm_128<<<dim3(8, 32, 1), dim3(512), 0, stream>>>(g2, flag);
}